// Round 15
// baseline (1050.353 us; speedup 1.0000x reference)
//
#include <hip/hip_runtime.h>
#include <hip/hip_bf16.h>

// TreeLSTM on MI355X. B=256 trees, 256 leaves (depth 9), H=512, C=5.
// f32 I/O; bf16 MFMA; f32 cell state. Output f32 [256,511,5].
//
// R15 = R14 (871us) with level128 rebuilt: A-fragments loaded DIRECTLY from
// global (frag == row-major 16B/lane, 16 full cachelines/frag) with one-k-step
// register double-buffer; only B staged in LDS. LDS bytes/k-step/block 81KB->40KB
// (measured R14: MfmaUtil 29.7% == exact LDS-BW ceiling; new ceiling ~60%).
// Leaf/BM=64 tail/logits/launcher identical to R14.

typedef __bf16 bf16;
typedef bf16  bf16x8 __attribute__((ext_vector_type(8)));
typedef float f32x4  __attribute__((ext_vector_type(4)));

__device__ __forceinline__ float sigm(float x){ return 1.0f/(1.0f + __expf(-x)); }
__device__ __forceinline__ float tanh_f(float x){ return 1.0f - 2.0f/(__expf(2.0f*x)+1.0f); }

// ---- converts ----
__global__ void cvt_pad_w(const float* __restrict__ src, bf16* __restrict__ dst){
  const int row = blockIdx.x, c = threadIdx.x;   // 1536 x 320
  dst[row*320 + c] = (bf16)(c < 300 ? src[row*300 + c] : 0.f);
}
__global__ void cvt_emb(const float* __restrict__ src, bf16* __restrict__ dst){
  const int row = blockIdx.x, c = threadIdx.x;   // 32000 x 320
  dst[row*320 + c] = (bf16)(c < 300 ? src[(size_t)row*300 + c] : 0.f);
}
__global__ void cvt_u(const float* __restrict__ Uiou, const float* __restrict__ Uf,
                      bf16* __restrict__ dst){
  const int i = blockIdx.x*256 + threadIdx.x;
  if (i < 2560*1024)
    dst[i] = (bf16)(i < 1536*1024 ? Uiou[i] : Uf[i - 1536*1024]);
}

// ---- leaf BM=128 (R12/R14, proven): x=embp[wordid]; iou = x @ W_iou^T + b; cell ----
__global__ __launch_bounds__(256, 2)
void leaf128_kernel(const int* __restrict__ wordid, const bf16* __restrict__ embp,
                    const bf16* __restrict__ Wpad, const float* __restrict__ Wb,
                    bf16* __restrict__ hcur, float* __restrict__ ccur)
{
  __shared__ bf16 lsA[128*40];
  __shared__ bf16 lsB[3][64*40];
  const int t = threadIdx.x;
  const int mrow0 = blockIdx.x*128, nblk = blockIdx.y*64;
  const int r = t>>2, kc = (t&3)*8;
  const int lane16 = t&15, quad = (t&63)>>4, w = t>>6;

  f32x4 acc[3][8];
  const f32x4 zero = {0.f,0.f,0.f,0.f};
  #pragma unroll
  for(int o=0;o<3;o++){
    #pragma unroll
    for(int rt=0;rt<8;rt++) acc[o][rt]=zero;
  }

  const int wid0 = wordid[mrow0 + r];
  const int wid1 = wordid[mrow0 + 64 + r];
  const bf16* arow0 = embp + (size_t)wid0*320;
  const bf16* arow1 = embp + (size_t)wid1*320;
  const int col = nblk + r;
  for (int k0=0;k0<320;k0+=32){
    *(bf16x8*)&lsA[r*40+kc]      = *(const bf16x8*)&arow0[k0+kc];
    *(bf16x8*)&lsA[(64+r)*40+kc] = *(const bf16x8*)&arow1[k0+kc];
    #pragma unroll
    for(int g=0;g<3;g++)
      *(bf16x8*)&lsB[g][r*40+kc] = *(const bf16x8*)&Wpad[(size_t)(g*512+col)*320 + k0+kc];
    __syncthreads();
    bf16x8 bfrag[3];
    #pragma unroll
    for(int g=0;g<3;g++) bfrag[g] = *(const bf16x8*)&lsB[g][(w*16+lane16)*40 + quad*8];
    #pragma unroll
    for(int rt=0;rt<8;rt++){
      bf16x8 a = *(const bf16x8*)&lsA[(rt*16+lane16)*40 + quad*8];
      #pragma unroll
      for(int g=0;g<3;g++)
        acc[g][rt] = __builtin_amdgcn_mfma_f32_16x16x32_bf16(a, bfrag[g], acc[g][rt], 0,0,0);
    }
    __syncthreads();
  }
  const int j = nblk + w*16 + lane16;
  const float bi=Wb[j], bo=Wb[512+j], bu=Wb[1024+j];
  #pragma unroll
  for(int rt=0;rt<8;rt++){
    #pragma unroll
    for(int reg=0;reg<4;reg++){
      const int row = mrow0 + rt*16 + quad*4 + reg;   // C/D: row=quad*4+reg, col=lane16
      float iv=acc[0][rt][reg]+bi, ov=acc[1][rt][reg]+bo, uv=acc[2][rt][reg]+bu;
      float c = sigm(iv)*tanh_f(uv);
      float h = sigm(ov)*tanh_f(c);
      ccur[(size_t)row*512 + j] = c;
      hcur[(size_t)row*512 + j] = (bf16)h;
    }
  }
}

// ---- level BM=64 (R7 body, proven): small levels ----
__global__ __launch_bounds__(256)
void level_kernel(const bf16* __restrict__ hprev, bf16* __restrict__ hcur,
                  const float* __restrict__ cprev, float* __restrict__ ccur,
                  const bf16* __restrict__ Uall, const float* __restrict__ Uioub,
                  const float* __restrict__ Ufb)
{
  __shared__ bf16 lsA[64*40];
  __shared__ bf16 lsB[5][64*40];
  const int t = threadIdx.x;
  const int mrow0 = blockIdx.x*64, nblk = blockIdx.y*64;
  const int r = t>>2, kc = (t&3)*8;
  const int lane16 = t&15, quad = (t&63)>>4, w = t>>6;

  f32x4 acc[5][4];
  const f32x4 zero = {0.f,0.f,0.f,0.f};
  #pragma unroll
  for(int o=0;o<5;o++){
    #pragma unroll
    for(int rt=0;rt<4;rt++) acc[o][rt]=zero;
  }

  const bf16* arow = hprev + (size_t)(mrow0 + r)*1024;
  const int col = nblk + r;
  for (int k0=0;k0<1024;k0+=32){
    *(bf16x8*)&lsA[r*40+kc] = *(const bf16x8*)&arow[k0+kc];
    #pragma unroll
    for(int g=0;g<5;g++)
      *(bf16x8*)&lsB[g][r*40+kc] = *(const bf16x8*)&Uall[(size_t)(g*512+col)*1024 + k0+kc];
    __syncthreads();
    bf16x8 bfrag[5];
    #pragma unroll
    for(int o=0;o<5;o++) bfrag[o] = *(const bf16x8*)&lsB[o][(w*16+lane16)*40 + quad*8];
    #pragma unroll
    for(int rt=0;rt<4;rt++){
      bf16x8 a = *(const bf16x8*)&lsA[(rt*16+lane16)*40 + quad*8];
      #pragma unroll
      for(int o=0;o<5;o++)
        acc[o][rt] = __builtin_amdgcn_mfma_f32_16x16x32_bf16(a, bfrag[o], acc[o][rt], 0,0,0);
    }
    __syncthreads();
  }
  const int j = nblk + w*16 + lane16;
  const float bi =Uioub[j], bo=Uioub[512+j], bu=Uioub[1024+j];
  const float bfl=Ufb[j],   bfr=Ufb[512+j];
  #pragma unroll
  for(int rt=0;rt<4;rt++){
    #pragma unroll
    for(int reg=0;reg<4;reg++){
      const int row = mrow0 + rt*16 + quad*4 + reg;
      float iv=acc[0][rt][reg]+bi, ov=acc[1][rt][reg]+bo, uv=acc[2][rt][reg]+bu;
      float fl=acc[3][rt][reg]+bfl, fr=acc[4][rt][reg]+bfr;
      float cl = cprev[((size_t)row*2  )*512 + j];
      float cr = cprev[((size_t)row*2+1)*512 + j];
      float cf = sigm(fl)*cl + sigm(fr)*cr;
      float c  = sigm(iv)*tanh_f(uv) + cf;
      float h  = sigm(ov)*tanh_f(c);
      ccur[(size_t)row*512 + j] = c;
      hcur[(size_t)row*512 + j] = (bf16)h;
    }
  }
}

// ---- level BM=128, A direct from global w/ register double-buffer; B in LDS ----
__global__ __launch_bounds__(256, 2)
void level128_kernel(const bf16* __restrict__ hprev, bf16* __restrict__ hcur,
                     const float* __restrict__ cprev, float* __restrict__ ccur,
                     const bf16* __restrict__ Uall, const float* __restrict__ Uioub,
                     const float* __restrict__ Ufb)
{
  __shared__ bf16 lsB[5][64*40];   // 25 KB, B only
  const int t = threadIdx.x;
  const int mrow0 = blockIdx.x*128, nblk = blockIdx.y*64;
  const int r = t>>2, kc = (t&3)*8;
  const int lane16 = t&15, quad = (t&63)>>4, w = t>>6;

  f32x4 acc[5][8];
  const f32x4 zero = {0.f,0.f,0.f,0.f};
  #pragma unroll
  for(int o=0;o<5;o++){
    #pragma unroll
    for(int rt=0;rt<8;rt++) acc[o][rt]=zero;
  }

  // A-frag base: lane l reads row (mrow0 + rt*16 + lane16), k-octet quad.
  // One frag = 16 rows x 16B at 4 k-octets = 16 full 64B lines (coalesced).
  const bf16* gA = hprev + (size_t)(mrow0 + lane16)*1024 + quad*8;
  const int col = nblk + r;
  const bf16* gBb = Uall + (size_t)col*1024 + kc;   // + g*512*1024 + ks*32

  bf16x8 a_cur[8], a_nxt[8];
  // prologue: A for ks=0, stage B for ks=0
  #pragma unroll
  for(int rt=0;rt<8;rt++) a_cur[rt] = *(const bf16x8*)(gA + (size_t)rt*16*1024);
  {
    bf16x8 sb[5];
    #pragma unroll
    for(int g=0;g<5;g++) sb[g] = *(const bf16x8*)(gBb + (size_t)g*512*1024);
    #pragma unroll
    for(int g=0;g<5;g++) *(bf16x8*)&lsB[g][r*40+kc] = sb[g];
  }
  __syncthreads();

  for (int ks=0; ks<32; ks++){
    bf16x8 sbn[5];
    if (ks < 31){
      const int k1 = (ks+1)*32;
      #pragma unroll
      for(int rt=0;rt<8;rt++) a_nxt[rt] = *(const bf16x8*)(gA + (size_t)rt*16*1024 + k1);
      #pragma unroll
      for(int g=0;g<5;g++) sbn[g] = *(const bf16x8*)(gBb + (size_t)g*512*1024 + k1);
    }
    bf16x8 bfrag[5];
    #pragma unroll
    for(int g=0;g<5;g++) bfrag[g] = *(const bf16x8*)&lsB[g][(w*16+lane16)*40 + quad*8];
    #pragma unroll
    for(int rt=0;rt<8;rt++){
      #pragma unroll
      for(int g=0;g<5;g++)
        acc[g][rt] = __builtin_amdgcn_mfma_f32_16x16x32_bf16(a_cur[rt], bfrag[g], acc[g][rt], 0,0,0);
    }
    if (ks < 31){
      __syncthreads();
      #pragma unroll
      for(int g=0;g<5;g++) *(bf16x8*)&lsB[g][r*40+kc] = sbn[g];
      __syncthreads();
      #pragma unroll
      for(int rt=0;rt<8;rt++) a_cur[rt] = a_nxt[rt];
    }
  }

  const int j = nblk + w*16 + lane16;
  const float bi =Uioub[j], bo=Uioub[512+j], bu=Uioub[1024+j];
  const float bfl=Ufb[j],   bfr=Ufb[512+j];
  #pragma unroll
  for(int rt=0;rt<8;rt++){
    #pragma unroll
    for(int reg=0;reg<4;reg++){
      const int row = mrow0 + rt*16 + quad*4 + reg;
      float iv=acc[0][rt][reg]+bi, ov=acc[1][rt][reg]+bo, uv=acc[2][rt][reg]+bu;
      float fl=acc[3][rt][reg]+bfl, fr=acc[4][rt][reg]+bfr;
      float cl = cprev[((size_t)row*2  )*512 + j];
      float cr = cprev[((size_t)row*2+1)*512 + j];
      float cf = sigm(fl)*cl + sigm(fr)*cr;
      float c  = sigm(iv)*tanh_f(uv) + cf;
      float h  = sigm(ov)*tanh_f(c);
      ccur[(size_t)row*512 + j] = c;
      hcur[(size_t)row*512 + j] = (bf16)h;
    }
  }
}

// ---- logits: out[node*5+c] = h_row . lin_w[c] + lin_b[c] ----
__global__ __launch_bounds__(256)
void logits_kernel(const bf16* __restrict__ h, const float* __restrict__ linw,
                   const float* __restrict__ linb, float* __restrict__ out,
                   int rowbase, int lgm, int mask, int off){
  const int row = blockIdx.x*4 + (threadIdx.x>>6);
  const int l = threadIdx.x & 63;
  bf16x8 hv = *(const bf16x8*)(h + (size_t)row*512 + l*8);
  float hf[8];
  #pragma unroll
  for(int jj=0;jj<8;jj++) hf[jj] = (float)hv[jj];
  float s[5];
  #pragma unroll
  for(int c=0;c<5;c++){
    const f32x4 w0 = *(const f32x4*)(linw + c*512 + l*8);
    const f32x4 w1 = *(const f32x4*)(linw + c*512 + l*8 + 4);
    float a = 0.f;
    #pragma unroll
    for(int jj=0;jj<4;jj++) a += hf[jj]*w0[jj] + hf[4+jj]*w1[jj];
    s[c]=a;
  }
  #pragma unroll
  for(int o=32;o>0;o>>=1){
    #pragma unroll
    for(int c=0;c<5;c++) s[c] += __shfl_down(s[c], o, 64);
  }
  if (l==0){
    const int g = rowbase + row;
    const int node = (g>>lgm)*511 + off + (g&mask);
    #pragma unroll
    for(int c=0;c<5;c++) out[(size_t)node*5+c] = s[c] + linb[c];
  }
}

__global__ void zero_out(float* out, int n){
  int i = blockIdx.x*256 + threadIdx.x;
  if (i < n) out[i] = 0.f;
}

extern "C" void kernel_launch(void* const* d_in, const int* in_sizes, int n_in,
                              void* d_out, int out_size, void* d_ws, size_t ws_size,
                              hipStream_t stream)
{
  const int*   wordid = (const int*)d_in[0];
  const float* emb    = (const float*)d_in[1];
  const float* Wiou   = (const float*)d_in[2];
  const float* Wioub  = (const float*)d_in[3];
  const float* Uiou   = (const float*)d_in[4];
  const float* Uioub  = (const float*)d_in[5];
  const float* Uf     = (const float*)d_in[6];
  const float* Ufb    = (const float*)d_in[7];
  const float* linw   = (const float*)d_in[8];
  const float* linb   = (const float*)d_in[9];
  float* out = (float*)d_out;

  // ---- fixed-region layout (R7/R14) ----
  const size_t oWPD  = 0;
  const size_t oUALL = oWPD  + (size_t)1536*320*2;
  const size_t oEMB  = oUALL + (size_t)2560*1024*2;
  const size_t oH1   = oEMB  + (size_t)32000*320*2;
  const size_t oC1   = oH1   + (size_t)32768*512*2;
  const size_t oH0   = oC1   + (size_t)32768*512*4;
  size_t R0 = 0;
  {
    const size_t t2 = oH0 + (size_t)32768*512*(2+4);   // 228.0 MB
    const size_t t4 = oH0 + (size_t)16384*512*(2+4);   // 177.7 MB
    const size_t t8 = oH0 + (size_t) 8192*512*(2+4);   // 152.5 MB
    if      (ws_size >= t2) R0 = 32768;
    else if (ws_size >= t4) R0 = 16384;
    else if (ws_size >= t8) R0 = 8192;
  }
  if (R0 == 0){
    zero_out<<<(out_size+255)/256, 256, 0, stream>>>(out, out_size);
    return;
  }

  char* ws = (char*)d_ws;
  bf16*  Wpad = (bf16*)(ws + oWPD);
  bf16*  Uall = (bf16*)(ws + oUALL);
  bf16*  embp = (bf16*)(ws + oEMB);
  bf16*  h1   = (bf16*)(ws + oH1);
  float* c1   = (float*)(ws + oC1);
  bf16*  h0   = (bf16*)(ws + oH0);
  float* c0   = (float*)(ws + oH0 + R0*1024);

  cvt_pad_w<<<1536, 320, 0, stream>>>(Wiou, Wpad);
  cvt_u<<<(2560*1024+255)/256, 256, 0, stream>>>(Uiou, Uf, Uall);
  cvt_emb<<<32000, 320, 0, stream>>>(emb, embp);

  const int offs[9] = {0,256,384,448,480,496,504,508,510};
  const int nchunk = (int)(65536 / R0);

  // ---- leaf + level-1, chunked through h0/c0 scratch ----
  for (int ch = 0; ch < nchunk; ch++){
    const int* wid = wordid + (size_t)ch*R0;
    leaf128_kernel<<<dim3((int)(R0/128), 8), 256, 0, stream>>>(wid, embp, Wpad, Wioub,
                                                               h0, c0);
    logits_kernel<<<(int)(R0/4), 256, 0, stream>>>(h0, linw, linb, out,
                                                   (int)(ch*R0), 8, 255, 0);
    bf16*  h1c = h1 + (size_t)ch*(R0/2)*512;
    float* c1c = c1 + (size_t)ch*(R0/2)*512;
    const int orows = (int)(R0/2);
    level128_kernel<<<dim3(orows/128, 8), 256, 0, stream>>>(h0, h1c, c0, c1c,
                                                            Uall, Uioub, Ufb);
  }
  logits_kernel<<<32768/4, 256, 0, stream>>>(h1, linw, linb, out, 0, 7, 127, offs[1]);

  // ---- levels 2..8: ping-pong h1/c1 <-> h0/c0 regions ----
  for (int lv = 2; lv <= 8; lv++){
    const int rows = 65536 >> lv;
    const bf16*  hin  = (lv & 1) ? h0 : h1;
    bf16*        hout = (lv & 1) ? h1 : h0;
    const float* cin  = (lv & 1) ? c0 : c1;
    float*       cout = (lv & 1) ? c1 : c0;
    if (rows >= 4096)
      level128_kernel<<<dim3(rows/128, 8), 256, 0, stream>>>(hin, hout, cin, cout,
                                                             Uall, Uioub, Ufb);
    else
      level_kernel<<<dim3(rows/64, 8), 256, 0, stream>>>(hin, hout, cin, cout,
                                                         Uall, Uioub, Ufb);
    logits_kernel<<<rows/4, 256, 0, stream>>>(hout, linw, linb, out,
                                              0, 8-lv, (256>>lv)-1, offs[lv]);
  }
}

// Round 17
// 874.998 us; speedup vs baseline: 1.2004x; 1.2004x over previous
//
#include <hip/hip_runtime.h>
#include <hip/hip_bf16.h>

// TreeLSTM on MI355X. B=256 trees, 256 leaves (depth 9), H=512, C=5.
// f32 I/O; bf16 MFMA; f32 cell state. Output f32 [256,511,5].
//
// R17 = R14 verbatim (871us, all kernels proven) + ONE isolated change:
// merged cvt_all (3 convert dispatches -> 1). Fused-logits (R13/R16) retired
// after two unverifiable correctness failures.

typedef __bf16 bf16;
typedef bf16  bf16x8 __attribute__((ext_vector_type(8)));
typedef float f32x4  __attribute__((ext_vector_type(4)));

__device__ __forceinline__ float sigm(float x){ return 1.0f/(1.0f + __expf(-x)); }
__device__ __forceinline__ float tanh_f(float x){ return 1.0f - 2.0f/(__expf(2.0f*x)+1.0f); }

// ---- merged converts: Wpad | embp | Uall in one dispatch ----
__global__ void cvt_all(const float* __restrict__ Wiou, const float* __restrict__ Uiou,
                        const float* __restrict__ Uf, const float* __restrict__ emb,
                        bf16* __restrict__ Wpad, bf16* __restrict__ Uall,
                        bf16* __restrict__ embp){
  const int b = blockIdx.x, t = threadIdx.x;            // 320 threads
  if (b < 1536){
    Wpad[b*320 + t] = (bf16)(t < 300 ? Wiou[b*300 + t] : 0.f);
  } else if (b < 1536 + 32000){
    const int r = b - 1536;
    embp[(size_t)r*320 + t] = (bf16)(t < 300 ? emb[(size_t)r*300 + t] : 0.f);
  } else {
    const size_t i = (size_t)(b - 33536)*320 + t;       // 8192 blocks * 320 = 2560*1024
    if (i < (size_t)1536*1024) Uall[i] = (bf16)Uiou[i];
    else                       Uall[i] = (bf16)Uf[i - (size_t)1536*1024];
  }
}

// ---- leaf BM=128 (R12/R14, proven): x=embp[wordid]; iou = x @ W_iou^T + b; cell ----
__global__ __launch_bounds__(256, 2)
void leaf128_kernel(const int* __restrict__ wordid, const bf16* __restrict__ embp,
                    const bf16* __restrict__ Wpad, const float* __restrict__ Wb,
                    bf16* __restrict__ hcur, float* __restrict__ ccur)
{
  __shared__ bf16 lsA[128*40];
  __shared__ bf16 lsB[3][64*40];
  const int t = threadIdx.x;
  const int mrow0 = blockIdx.x*128, nblk = blockIdx.y*64;
  const int r = t>>2, kc = (t&3)*8;
  const int lane16 = t&15, quad = (t&63)>>4, w = t>>6;

  f32x4 acc[3][8];
  const f32x4 zero = {0.f,0.f,0.f,0.f};
  #pragma unroll
  for(int o=0;o<3;o++){
    #pragma unroll
    for(int rt=0;rt<8;rt++) acc[o][rt]=zero;
  }

  const int wid0 = wordid[mrow0 + r];
  const int wid1 = wordid[mrow0 + 64 + r];
  const bf16* arow0 = embp + (size_t)wid0*320;
  const bf16* arow1 = embp + (size_t)wid1*320;
  const int col = nblk + r;
  for (int k0=0;k0<320;k0+=32){
    *(bf16x8*)&lsA[r*40+kc]      = *(const bf16x8*)&arow0[k0+kc];
    *(bf16x8*)&lsA[(64+r)*40+kc] = *(const bf16x8*)&arow1[k0+kc];
    #pragma unroll
    for(int g=0;g<3;g++)
      *(bf16x8*)&lsB[g][r*40+kc] = *(const bf16x8*)&Wpad[(size_t)(g*512+col)*320 + k0+kc];
    __syncthreads();
    bf16x8 bfrag[3];
    #pragma unroll
    for(int g=0;g<3;g++) bfrag[g] = *(const bf16x8*)&lsB[g][(w*16+lane16)*40 + quad*8];
    #pragma unroll
    for(int rt=0;rt<8;rt++){
      bf16x8 a = *(const bf16x8*)&lsA[(rt*16+lane16)*40 + quad*8];
      #pragma unroll
      for(int g=0;g<3;g++)
        acc[g][rt] = __builtin_amdgcn_mfma_f32_16x16x32_bf16(a, bfrag[g], acc[g][rt], 0,0,0);
    }
    __syncthreads();
  }
  const int j = nblk + w*16 + lane16;
  const float bi=Wb[j], bo=Wb[512+j], bu=Wb[1024+j];
  #pragma unroll
  for(int rt=0;rt<8;rt++){
    #pragma unroll
    for(int reg=0;reg<4;reg++){
      const int row = mrow0 + rt*16 + quad*4 + reg;   // C/D: row=quad*4+reg, col=lane16
      float iv=acc[0][rt][reg]+bi, ov=acc[1][rt][reg]+bo, uv=acc[2][rt][reg]+bu;
      float c = sigm(iv)*tanh_f(uv);
      float h = sigm(ov)*tanh_f(c);
      ccur[(size_t)row*512 + j] = c;
      hcur[(size_t)row*512 + j] = (bf16)h;
    }
  }
}

// ---- level BM=64 (R7 body, proven): small levels ----
__global__ __launch_bounds__(256)
void level_kernel(const bf16* __restrict__ hprev, bf16* __restrict__ hcur,
                  const float* __restrict__ cprev, float* __restrict__ ccur,
                  const bf16* __restrict__ Uall, const float* __restrict__ Uioub,
                  const float* __restrict__ Ufb)
{
  __shared__ bf16 lsA[64*40];
  __shared__ bf16 lsB[5][64*40];
  const int t = threadIdx.x;
  const int mrow0 = blockIdx.x*64, nblk = blockIdx.y*64;
  const int r = t>>2, kc = (t&3)*8;
  const int lane16 = t&15, quad = (t&63)>>4, w = t>>6;

  f32x4 acc[5][4];
  const f32x4 zero = {0.f,0.f,0.f,0.f};
  #pragma unroll
  for(int o=0;o<5;o++){
    #pragma unroll
    for(int rt=0;rt<4;rt++) acc[o][rt]=zero;
  }

  const bf16* arow = hprev + (size_t)(mrow0 + r)*1024;
  const int col = nblk + r;
  for (int k0=0;k0<1024;k0+=32){
    *(bf16x8*)&lsA[r*40+kc] = *(const bf16x8*)&arow[k0+kc];
    #pragma unroll
    for(int g=0;g<5;g++)
      *(bf16x8*)&lsB[g][r*40+kc] = *(const bf16x8*)&Uall[(size_t)(g*512+col)*1024 + k0+kc];
    __syncthreads();
    bf16x8 bfrag[5];
    #pragma unroll
    for(int o=0;o<5;o++) bfrag[o] = *(const bf16x8*)&lsB[o][(w*16+lane16)*40 + quad*8];
    #pragma unroll
    for(int rt=0;rt<4;rt++){
      bf16x8 a = *(const bf16x8*)&lsA[(rt*16+lane16)*40 + quad*8];
      #pragma unroll
      for(int o=0;o<5;o++)
        acc[o][rt] = __builtin_amdgcn_mfma_f32_16x16x32_bf16(a, bfrag[o], acc[o][rt], 0,0,0);
    }
    __syncthreads();
  }
  const int j = nblk + w*16 + lane16;
  const float bi =Uioub[j], bo=Uioub[512+j], bu=Uioub[1024+j];
  const float bfl=Ufb[j],   bfr=Ufb[512+j];
  #pragma unroll
  for(int rt=0;rt<4;rt++){
    #pragma unroll
    for(int reg=0;reg<4;reg++){
      const int row = mrow0 + rt*16 + quad*4 + reg;
      float iv=acc[0][rt][reg]+bi, ov=acc[1][rt][reg]+bo, uv=acc[2][rt][reg]+bu;
      float fl=acc[3][rt][reg]+bfl, fr=acc[4][rt][reg]+bfr;
      float cl = cprev[((size_t)row*2  )*512 + j];
      float cr = cprev[((size_t)row*2+1)*512 + j];
      float cf = sigm(fl)*cl + sigm(fr)*cr;
      float c  = sigm(iv)*tanh_f(uv) + cf;
      float h  = sigm(ov)*tanh_f(c);
      ccur[(size_t)row*512 + j] = c;
      hcur[(size_t)row*512 + j] = (bf16)h;
    }
  }
}

// ---- level BM=128 (R11/R14, proven): big levels ----
__global__ __launch_bounds__(256, 2)
void level128_kernel(const bf16* __restrict__ hprev, bf16* __restrict__ hcur,
                     const float* __restrict__ cprev, float* __restrict__ ccur,
                     const bf16* __restrict__ Uall, const float* __restrict__ Uioub,
                     const float* __restrict__ Ufb)
{
  __shared__ bf16 lsA[128*40];
  __shared__ bf16 lsB[5][64*40];
  const int t = threadIdx.x;
  const int mrow0 = blockIdx.x*128, nblk = blockIdx.y*64;
  const int r = t>>2, kc = (t&3)*8;
  const int lane16 = t&15, quad = (t&63)>>4, w = t>>6;

  f32x4 acc[5][8];
  const f32x4 zero = {0.f,0.f,0.f,0.f};
  #pragma unroll
  for(int o=0;o<5;o++){
    #pragma unroll
    for(int rt=0;rt<8;rt++) acc[o][rt]=zero;
  }

  const bf16* arow0 = hprev + (size_t)(mrow0 + r)*1024;
  const bf16* arow1 = hprev + (size_t)(mrow0 + 64 + r)*1024;
  const int col = nblk + r;
  for (int k0=0;k0<1024;k0+=32){
    *(bf16x8*)&lsA[r*40+kc]      = *(const bf16x8*)&arow0[k0+kc];
    *(bf16x8*)&lsA[(64+r)*40+kc] = *(const bf16x8*)&arow1[k0+kc];
    #pragma unroll
    for(int g=0;g<5;g++)
      *(bf16x8*)&lsB[g][r*40+kc] = *(const bf16x8*)&Uall[(size_t)(g*512+col)*1024 + k0+kc];
    __syncthreads();
    bf16x8 bfrag[5];
    #pragma unroll
    for(int g=0;g<5;g++) bfrag[g] = *(const bf16x8*)&lsB[g][(w*16+lane16)*40 + quad*8];
    #pragma unroll
    for(int rt=0;rt<8;rt++){
      bf16x8 a = *(const bf16x8*)&lsA[(rt*16+lane16)*40 + quad*8];
      #pragma unroll
      for(int g=0;g<5;g++)
        acc[g][rt] = __builtin_amdgcn_mfma_f32_16x16x32_bf16(a, bfrag[g], acc[g][rt], 0,0,0);
    }
    __syncthreads();
  }
  const int j = nblk + w*16 + lane16;
  const float bi =Uioub[j], bo=Uioub[512+j], bu=Uioub[1024+j];
  const float bfl=Ufb[j],   bfr=Ufb[512+j];
  #pragma unroll
  for(int rt=0;rt<8;rt++){
    #pragma unroll
    for(int reg=0;reg<4;reg++){
      const int row = mrow0 + rt*16 + quad*4 + reg;
      float iv=acc[0][rt][reg]+bi, ov=acc[1][rt][reg]+bo, uv=acc[2][rt][reg]+bu;
      float fl=acc[3][rt][reg]+bfl, fr=acc[4][rt][reg]+bfr;
      float cl = cprev[((size_t)row*2  )*512 + j];
      float cr = cprev[((size_t)row*2+1)*512 + j];
      float cf = sigm(fl)*cl + sigm(fr)*cr;
      float c  = sigm(iv)*tanh_f(uv) + cf;
      float h  = sigm(ov)*tanh_f(c);
      ccur[(size_t)row*512 + j] = c;
      hcur[(size_t)row*512 + j] = (bf16)h;
    }
  }
}

// ---- logits: out[node*5+c] = h_row . lin_w[c] + lin_b[c] ----
__global__ __launch_bounds__(256)
void logits_kernel(const bf16* __restrict__ h, const float* __restrict__ linw,
                   const float* __restrict__ linb, float* __restrict__ out,
                   int rowbase, int lgm, int mask, int off){
  const int row = blockIdx.x*4 + (threadIdx.x>>6);
  const int l = threadIdx.x & 63;
  bf16x8 hv = *(const bf16x8*)(h + (size_t)row*512 + l*8);
  float hf[8];
  #pragma unroll
  for(int jj=0;jj<8;jj++) hf[jj] = (float)hv[jj];
  float s[5];
  #pragma unroll
  for(int c=0;c<5;c++){
    const f32x4 w0 = *(const f32x4*)(linw + c*512 + l*8);
    const f32x4 w1 = *(const f32x4*)(linw + c*512 + l*8 + 4);
    float a = 0.f;
    #pragma unroll
    for(int jj=0;jj<4;jj++) a += hf[jj]*w0[jj] + hf[4+jj]*w1[jj];
    s[c]=a;
  }
  #pragma unroll
  for(int o=32;o>0;o>>=1){
    #pragma unroll
    for(int c=0;c<5;c++) s[c] += __shfl_down(s[c], o, 64);
  }
  if (l==0){
    const int g = rowbase + row;
    const int node = (g>>lgm)*511 + off + (g&mask);
    #pragma unroll
    for(int c=0;c<5;c++) out[(size_t)node*5+c] = s[c] + linb[c];
  }
}

__global__ void zero_out(float* out, int n){
  int i = blockIdx.x*256 + threadIdx.x;
  if (i < n) out[i] = 0.f;
}

extern "C" void kernel_launch(void* const* d_in, const int* in_sizes, int n_in,
                              void* d_out, int out_size, void* d_ws, size_t ws_size,
                              hipStream_t stream)
{
  const int*   wordid = (const int*)d_in[0];
  const float* emb    = (const float*)d_in[1];
  const float* Wiou   = (const float*)d_in[2];
  const float* Wioub  = (const float*)d_in[3];
  const float* Uiou   = (const float*)d_in[4];
  const float* Uioub  = (const float*)d_in[5];
  const float* Uf     = (const float*)d_in[6];
  const float* Ufb    = (const float*)d_in[7];
  const float* linw   = (const float*)d_in[8];
  const float* linb   = (const float*)d_in[9];
  float* out = (float*)d_out;

  // ---- fixed-region layout (R7/R14) ----
  const size_t oWPD  = 0;
  const size_t oUALL = oWPD  + (size_t)1536*320*2;
  const size_t oEMB  = oUALL + (size_t)2560*1024*2;
  const size_t oH1   = oEMB  + (size_t)32000*320*2;
  const size_t oC1   = oH1   + (size_t)32768*512*2;
  const size_t oH0   = oC1   + (size_t)32768*512*4;
  size_t R0 = 0;
  {
    const size_t t2 = oH0 + (size_t)32768*512*(2+4);   // 228.0 MB
    const size_t t4 = oH0 + (size_t)16384*512*(2+4);   // 177.7 MB
    const size_t t8 = oH0 + (size_t) 8192*512*(2+4);   // 152.5 MB
    if      (ws_size >= t2) R0 = 32768;
    else if (ws_size >= t4) R0 = 16384;
    else if (ws_size >= t8) R0 = 8192;
  }
  if (R0 == 0){
    zero_out<<<(out_size+255)/256, 256, 0, stream>>>(out, out_size);
    return;
  }

  char* ws = (char*)d_ws;
  bf16*  Wpad = (bf16*)(ws + oWPD);
  bf16*  Uall = (bf16*)(ws + oUALL);
  bf16*  embp = (bf16*)(ws + oEMB);
  bf16*  h1   = (bf16*)(ws + oH1);
  float* c1   = (float*)(ws + oC1);
  bf16*  h0   = (bf16*)(ws + oH0);
  float* c0   = (float*)(ws + oH0 + R0*1024);

  cvt_all<<<41728, 320, 0, stream>>>(Wiou, Uiou, Uf, emb, Wpad, Uall, embp);

  const int offs[9] = {0,256,384,448,480,496,504,508,510};
  const int nchunk = (int)(65536 / R0);

  // ---- leaf + level-1, chunked through h0/c0 scratch ----
  for (int ch = 0; ch < nchunk; ch++){
    const int* wid = wordid + (size_t)ch*R0;
    leaf128_kernel<<<dim3((int)(R0/128), 8), 256, 0, stream>>>(wid, embp, Wpad, Wioub,
                                                               h0, c0);
    logits_kernel<<<(int)(R0/4), 256, 0, stream>>>(h0, linw, linb, out,
                                                   (int)(ch*R0), 8, 255, 0);
    bf16*  h1c = h1 + (size_t)ch*(R0/2)*512;
    float* c1c = c1 + (size_t)ch*(R0/2)*512;
    const int orows = (int)(R0/2);
    level128_kernel<<<dim3(orows/128, 8), 256, 0, stream>>>(h0, h1c, c0, c1c,
                                                            Uall, Uioub, Ufb);
  }
  logits_kernel<<<32768/4, 256, 0, stream>>>(h1, linw, linb, out, 0, 7, 127, offs[1]);

  // ---- levels 2..8: ping-pong h1/c1 <-> h0/c0 regions ----
  for (int lv = 2; lv <= 8; lv++){
    const int rows = 65536 >> lv;
    const bf16*  hin  = (lv & 1) ? h0 : h1;
    bf16*        hout = (lv & 1) ? h1 : h0;
    const float* cin  = (lv & 1) ? c0 : c1;
    float*       cout = (lv & 1) ? c1 : c0;
    if (rows >= 4096)
      level128_kernel<<<dim3(rows/128, 8), 256, 0, stream>>>(hin, hout, cin, cout,
                                                             Uall, Uioub, Ufb);
    else
      level_kernel<<<dim3(rows/64, 8), 256, 0, stream>>>(hin, hout, cin, cout,
                                                         Uall, Uioub, Ufb);
    logits_kernel<<<rows/4, 256, 0, stream>>>(hout, linw, linb, out,
                                              0, 8-lv, (256>>lv)-1, offs[lv]);
  }
}

// Round 18
// 857.122 us; speedup vs baseline: 1.2254x; 1.0209x over previous
//
#include <hip/hip_runtime.h>
#include <hip/hip_bf16.h>

// TreeLSTM on MI355X. B=256 trees, 256 leaves (depth 9), H=512, C=5.
// f32 I/O; bf16 MFMA; f32 cell state. Output f32 [256,511,5].
//
// R18 = R17 (875us, all kernels proven) + logits pairing: per-level logits for
// (lv1,lv2),(lv3,lv4),(lv5,lv6),(lv7,lv8) merged into 4 logits2 dispatches
// (verbatim GEMV, two source-pointer/param sets selected by row). Valid because
// after even lv, both lv-1's h (h1) and lv's h (h0) are still intact. 22->18
// dispatches. K-loop at verified LDS-BW structural ceiling (~30% MfmaUtil).

typedef __bf16 bf16;
typedef bf16  bf16x8 __attribute__((ext_vector_type(8)));
typedef float f32x4  __attribute__((ext_vector_type(4)));

__device__ __forceinline__ float sigm(float x){ return 1.0f/(1.0f + __expf(-x)); }
__device__ __forceinline__ float tanh_f(float x){ return 1.0f - 2.0f/(__expf(2.0f*x)+1.0f); }

// ---- merged converts: Wpad | embp | Uall in one dispatch (proven R17) ----
__global__ void cvt_all(const float* __restrict__ Wiou, const float* __restrict__ Uiou,
                        const float* __restrict__ Uf, const float* __restrict__ emb,
                        bf16* __restrict__ Wpad, bf16* __restrict__ Uall,
                        bf16* __restrict__ embp){
  const int b = blockIdx.x, t = threadIdx.x;            // 320 threads
  if (b < 1536){
    Wpad[b*320 + t] = (bf16)(t < 300 ? Wiou[b*300 + t] : 0.f);
  } else if (b < 1536 + 32000){
    const int r = b - 1536;
    embp[(size_t)r*320 + t] = (bf16)(t < 300 ? emb[(size_t)r*300 + t] : 0.f);
  } else {
    const size_t i = (size_t)(b - 33536)*320 + t;       // 8192 blocks * 320 = 2560*1024
    if (i < (size_t)1536*1024) Uall[i] = (bf16)Uiou[i];
    else                       Uall[i] = (bf16)Uf[i - (size_t)1536*1024];
  }
}

// ---- leaf BM=128 (R12/R14, proven) ----
__global__ __launch_bounds__(256, 2)
void leaf128_kernel(const int* __restrict__ wordid, const bf16* __restrict__ embp,
                    const bf16* __restrict__ Wpad, const float* __restrict__ Wb,
                    bf16* __restrict__ hcur, float* __restrict__ ccur)
{
  __shared__ bf16 lsA[128*40];
  __shared__ bf16 lsB[3][64*40];
  const int t = threadIdx.x;
  const int mrow0 = blockIdx.x*128, nblk = blockIdx.y*64;
  const int r = t>>2, kc = (t&3)*8;
  const int lane16 = t&15, quad = (t&63)>>4, w = t>>6;

  f32x4 acc[3][8];
  const f32x4 zero = {0.f,0.f,0.f,0.f};
  #pragma unroll
  for(int o=0;o<3;o++){
    #pragma unroll
    for(int rt=0;rt<8;rt++) acc[o][rt]=zero;
  }

  const int wid0 = wordid[mrow0 + r];
  const int wid1 = wordid[mrow0 + 64 + r];
  const bf16* arow0 = embp + (size_t)wid0*320;
  const bf16* arow1 = embp + (size_t)wid1*320;
  const int col = nblk + r;
  for (int k0=0;k0<320;k0+=32){
    *(bf16x8*)&lsA[r*40+kc]      = *(const bf16x8*)&arow0[k0+kc];
    *(bf16x8*)&lsA[(64+r)*40+kc] = *(const bf16x8*)&arow1[k0+kc];
    #pragma unroll
    for(int g=0;g<3;g++)
      *(bf16x8*)&lsB[g][r*40+kc] = *(const bf16x8*)&Wpad[(size_t)(g*512+col)*320 + k0+kc];
    __syncthreads();
    bf16x8 bfrag[3];
    #pragma unroll
    for(int g=0;g<3;g++) bfrag[g] = *(const bf16x8*)&lsB[g][(w*16+lane16)*40 + quad*8];
    #pragma unroll
    for(int rt=0;rt<8;rt++){
      bf16x8 a = *(const bf16x8*)&lsA[(rt*16+lane16)*40 + quad*8];
      #pragma unroll
      for(int g=0;g<3;g++)
        acc[g][rt] = __builtin_amdgcn_mfma_f32_16x16x32_bf16(a, bfrag[g], acc[g][rt], 0,0,0);
    }
    __syncthreads();
  }
  const int j = nblk + w*16 + lane16;
  const float bi=Wb[j], bo=Wb[512+j], bu=Wb[1024+j];
  #pragma unroll
  for(int rt=0;rt<8;rt++){
    #pragma unroll
    for(int reg=0;reg<4;reg++){
      const int row = mrow0 + rt*16 + quad*4 + reg;   // C/D: row=quad*4+reg, col=lane16
      float iv=acc[0][rt][reg]+bi, ov=acc[1][rt][reg]+bo, uv=acc[2][rt][reg]+bu;
      float c = sigm(iv)*tanh_f(uv);
      float h = sigm(ov)*tanh_f(c);
      ccur[(size_t)row*512 + j] = c;
      hcur[(size_t)row*512 + j] = (bf16)h;
    }
  }
}

// ---- level BM=64 (R7 body, proven): small levels ----
__global__ __launch_bounds__(256)
void level_kernel(const bf16* __restrict__ hprev, bf16* __restrict__ hcur,
                  const float* __restrict__ cprev, float* __restrict__ ccur,
                  const bf16* __restrict__ Uall, const float* __restrict__ Uioub,
                  const float* __restrict__ Ufb)
{
  __shared__ bf16 lsA[64*40];
  __shared__ bf16 lsB[5][64*40];
  const int t = threadIdx.x;
  const int mrow0 = blockIdx.x*64, nblk = blockIdx.y*64;
  const int r = t>>2, kc = (t&3)*8;
  const int lane16 = t&15, quad = (t&63)>>4, w = t>>6;

  f32x4 acc[5][4];
  const f32x4 zero = {0.f,0.f,0.f,0.f};
  #pragma unroll
  for(int o=0;o<5;o++){
    #pragma unroll
    for(int rt=0;rt<4;rt++) acc[o][rt]=zero;
  }

  const bf16* arow = hprev + (size_t)(mrow0 + r)*1024;
  const int col = nblk + r;
  for (int k0=0;k0<1024;k0+=32){
    *(bf16x8*)&lsA[r*40+kc] = *(const bf16x8*)&arow[k0+kc];
    #pragma unroll
    for(int g=0;g<5;g++)
      *(bf16x8*)&lsB[g][r*40+kc] = *(const bf16x8*)&Uall[(size_t)(g*512+col)*1024 + k0+kc];
    __syncthreads();
    bf16x8 bfrag[5];
    #pragma unroll
    for(int o=0;o<5;o++) bfrag[o] = *(const bf16x8*)&lsB[o][(w*16+lane16)*40 + quad*8];
    #pragma unroll
    for(int rt=0;rt<4;rt++){
      bf16x8 a = *(const bf16x8*)&lsA[(rt*16+lane16)*40 + quad*8];
      #pragma unroll
      for(int o=0;o<5;o++)
        acc[o][rt] = __builtin_amdgcn_mfma_f32_16x16x32_bf16(a, bfrag[o], acc[o][rt], 0,0,0);
    }
    __syncthreads();
  }
  const int j = nblk + w*16 + lane16;
  const float bi =Uioub[j], bo=Uioub[512+j], bu=Uioub[1024+j];
  const float bfl=Ufb[j],   bfr=Ufb[512+j];
  #pragma unroll
  for(int rt=0;rt<4;rt++){
    #pragma unroll
    for(int reg=0;reg<4;reg++){
      const int row = mrow0 + rt*16 + quad*4 + reg;
      float iv=acc[0][rt][reg]+bi, ov=acc[1][rt][reg]+bo, uv=acc[2][rt][reg]+bu;
      float fl=acc[3][rt][reg]+bfl, fr=acc[4][rt][reg]+bfr;
      float cl = cprev[((size_t)row*2  )*512 + j];
      float cr = cprev[((size_t)row*2+1)*512 + j];
      float cf = sigm(fl)*cl + sigm(fr)*cr;
      float c  = sigm(iv)*tanh_f(uv) + cf;
      float h  = sigm(ov)*tanh_f(c);
      ccur[(size_t)row*512 + j] = c;
      hcur[(size_t)row*512 + j] = (bf16)h;
    }
  }
}

// ---- level BM=128 (R11/R14, proven): big levels ----
__global__ __launch_bounds__(256, 2)
void level128_kernel(const bf16* __restrict__ hprev, bf16* __restrict__ hcur,
                     const float* __restrict__ cprev, float* __restrict__ ccur,
                     const bf16* __restrict__ Uall, const float* __restrict__ Uioub,
                     const float* __restrict__ Ufb)
{
  __shared__ bf16 lsA[128*40];
  __shared__ bf16 lsB[5][64*40];
  const int t = threadIdx.x;
  const int mrow0 = blockIdx.x*128, nblk = blockIdx.y*64;
  const int r = t>>2, kc = (t&3)*8;
  const int lane16 = t&15, quad = (t&63)>>4, w = t>>6;

  f32x4 acc[5][8];
  const f32x4 zero = {0.f,0.f,0.f,0.f};
  #pragma unroll
  for(int o=0;o<5;o++){
    #pragma unroll
    for(int rt=0;rt<8;rt++) acc[o][rt]=zero;
  }

  const bf16* arow0 = hprev + (size_t)(mrow0 + r)*1024;
  const bf16* arow1 = hprev + (size_t)(mrow0 + 64 + r)*1024;
  const int col = nblk + r;
  for (int k0=0;k0<1024;k0+=32){
    *(bf16x8*)&lsA[r*40+kc]      = *(const bf16x8*)&arow0[k0+kc];
    *(bf16x8*)&lsA[(64+r)*40+kc] = *(const bf16x8*)&arow1[k0+kc];
    #pragma unroll
    for(int g=0;g<5;g++)
      *(bf16x8*)&lsB[g][r*40+kc] = *(const bf16x8*)&Uall[(size_t)(g*512+col)*1024 + k0+kc];
    __syncthreads();
    bf16x8 bfrag[5];
    #pragma unroll
    for(int g=0;g<5;g++) bfrag[g] = *(const bf16x8*)&lsB[g][(w*16+lane16)*40 + quad*8];
    #pragma unroll
    for(int rt=0;rt<8;rt++){
      bf16x8 a = *(const bf16x8*)&lsA[(rt*16+lane16)*40 + quad*8];
      #pragma unroll
      for(int g=0;g<5;g++)
        acc[g][rt] = __builtin_amdgcn_mfma_f32_16x16x32_bf16(a, bfrag[g], acc[g][rt], 0,0,0);
    }
    __syncthreads();
  }
  const int j = nblk + w*16 + lane16;
  const float bi =Uioub[j], bo=Uioub[512+j], bu=Uioub[1024+j];
  const float bfl=Ufb[j],   bfr=Ufb[512+j];
  #pragma unroll
  for(int rt=0;rt<8;rt++){
    #pragma unroll
    for(int reg=0;reg<4;reg++){
      const int row = mrow0 + rt*16 + quad*4 + reg;
      float iv=acc[0][rt][reg]+bi, ov=acc[1][rt][reg]+bo, uv=acc[2][rt][reg]+bu;
      float fl=acc[3][rt][reg]+bfl, fr=acc[4][rt][reg]+bfr;
      float cl = cprev[((size_t)row*2  )*512 + j];
      float cr = cprev[((size_t)row*2+1)*512 + j];
      float cf = sigm(fl)*cl + sigm(fr)*cr;
      float c  = sigm(iv)*tanh_f(uv) + cf;
      float h  = sigm(ov)*tanh_f(c);
      ccur[(size_t)row*512 + j] = c;
      hcur[(size_t)row*512 + j] = (bf16)h;
    }
  }
}

// ---- logits (verbatim GEMV, proven): single-level version for leaf chunks ----
__global__ __launch_bounds__(256)
void logits_kernel(const bf16* __restrict__ h, const float* __restrict__ linw,
                   const float* __restrict__ linb, float* __restrict__ out,
                   int rowbase, int lgm, int mask, int off){
  const int row = blockIdx.x*4 + (threadIdx.x>>6);
  const int l = threadIdx.x & 63;
  bf16x8 hv = *(const bf16x8*)(h + (size_t)row*512 + l*8);
  float hf[8];
  #pragma unroll
  for(int jj=0;jj<8;jj++) hf[jj] = (float)hv[jj];
  float s[5];
  #pragma unroll
  for(int c=0;c<5;c++){
    const f32x4 w0 = *(const f32x4*)(linw + c*512 + l*8);
    const f32x4 w1 = *(const f32x4*)(linw + c*512 + l*8 + 4);
    float a = 0.f;
    #pragma unroll
    for(int jj=0;jj<4;jj++) a += hf[jj]*w0[jj] + hf[4+jj]*w1[jj];
    s[c]=a;
  }
  #pragma unroll
  for(int o=32;o>0;o>>=1){
    #pragma unroll
    for(int c=0;c<5;c++) s[c] += __shfl_down(s[c], o, 64);
  }
  if (l==0){
    const int g = rowbase + row;
    const int node = (g>>lgm)*511 + off + (g&mask);
    #pragma unroll
    for(int c=0;c<5;c++) out[(size_t)node*5+c] = s[c] + linb[c];
  }
}

// ---- logits2: two levels in one dispatch (same GEMV; per-row source select) ----
__global__ __launch_bounds__(256)
void logits2_kernel(const bf16* __restrict__ ha, int rows_a, int lgm_a, int mask_a, int off_a,
                    const bf16* __restrict__ hb, int lgm_b, int mask_b, int off_b,
                    const float* __restrict__ linw, const float* __restrict__ linb,
                    float* __restrict__ out){
  const int row = blockIdx.x*4 + (threadIdx.x>>6);
  const int l = threadIdx.x & 63;
  const bf16* hrow; int g, lgm, mask, off;
  if (row < rows_a){ hrow = ha + (size_t)row*512;            g = row;           lgm=lgm_a; mask=mask_a; off=off_a; }
  else             { hrow = hb + (size_t)(row-rows_a)*512;   g = row - rows_a;  lgm=lgm_b; mask=mask_b; off=off_b; }
  bf16x8 hv = *(const bf16x8*)(hrow + l*8);
  float hf[8];
  #pragma unroll
  for(int jj=0;jj<8;jj++) hf[jj] = (float)hv[jj];
  float s[5];
  #pragma unroll
  for(int c=0;c<5;c++){
    const f32x4 w0 = *(const f32x4*)(linw + c*512 + l*8);
    const f32x4 w1 = *(const f32x4*)(linw + c*512 + l*8 + 4);
    float a = 0.f;
    #pragma unroll
    for(int jj=0;jj<4;jj++) a += hf[jj]*w0[jj] + hf[4+jj]*w1[jj];
    s[c]=a;
  }
  #pragma unroll
  for(int o=32;o>0;o>>=1){
    #pragma unroll
    for(int c=0;c<5;c++) s[c] += __shfl_down(s[c], o, 64);
  }
  if (l==0){
    const int node = (g>>lgm)*511 + off + (g&mask);
    #pragma unroll
    for(int c=0;c<5;c++) out[(size_t)node*5+c] = s[c] + linb[c];
  }
}

__global__ void zero_out(float* out, int n){
  int i = blockIdx.x*256 + threadIdx.x;
  if (i < n) out[i] = 0.f;
}

extern "C" void kernel_launch(void* const* d_in, const int* in_sizes, int n_in,
                              void* d_out, int out_size, void* d_ws, size_t ws_size,
                              hipStream_t stream)
{
  const int*   wordid = (const int*)d_in[0];
  const float* emb    = (const float*)d_in[1];
  const float* Wiou   = (const float*)d_in[2];
  const float* Wioub  = (const float*)d_in[3];
  const float* Uiou   = (const float*)d_in[4];
  const float* Uioub  = (const float*)d_in[5];
  const float* Uf     = (const float*)d_in[6];
  const float* Ufb    = (const float*)d_in[7];
  const float* linw   = (const float*)d_in[8];
  const float* linb   = (const float*)d_in[9];
  float* out = (float*)d_out;

  // ---- fixed-region layout (R7/R14) ----
  const size_t oWPD  = 0;
  const size_t oUALL = oWPD  + (size_t)1536*320*2;
  const size_t oEMB  = oUALL + (size_t)2560*1024*2;
  const size_t oH1   = oEMB  + (size_t)32000*320*2;
  const size_t oC1   = oH1   + (size_t)32768*512*2;
  const size_t oH0   = oC1   + (size_t)32768*512*4;
  size_t R0 = 0;
  {
    const size_t t2 = oH0 + (size_t)32768*512*(2+4);   // 228.0 MB
    const size_t t4 = oH0 + (size_t)16384*512*(2+4);   // 177.7 MB
    const size_t t8 = oH0 + (size_t) 8192*512*(2+4);   // 152.5 MB
    if      (ws_size >= t2) R0 = 32768;
    else if (ws_size >= t4) R0 = 16384;
    else if (ws_size >= t8) R0 = 8192;
  }
  if (R0 == 0){
    zero_out<<<(out_size+255)/256, 256, 0, stream>>>(out, out_size);
    return;
  }

  char* ws = (char*)d_ws;
  bf16*  Wpad = (bf16*)(ws + oWPD);
  bf16*  Uall = (bf16*)(ws + oUALL);
  bf16*  embp = (bf16*)(ws + oEMB);
  bf16*  h1   = (bf16*)(ws + oH1);
  float* c1   = (float*)(ws + oC1);
  bf16*  h0   = (bf16*)(ws + oH0);
  float* c0   = (float*)(ws + oH0 + R0*1024);

  cvt_all<<<41728, 320, 0, stream>>>(Wiou, Uiou, Uf, emb, Wpad, Uall, embp);

  const int offs[9] = {0,256,384,448,480,496,504,508,510};
  const int nchunk = (int)(65536 / R0);

  // ---- leaf + level-1, chunked through h0/c0 scratch (leaf logits per chunk) ----
  for (int ch = 0; ch < nchunk; ch++){
    const int* wid = wordid + (size_t)ch*R0;
    leaf128_kernel<<<dim3((int)(R0/128), 8), 256, 0, stream>>>(wid, embp, Wpad, Wioub,
                                                               h0, c0);
    logits_kernel<<<(int)(R0/4), 256, 0, stream>>>(h0, linw, linb, out,
                                                   (int)(ch*R0), 8, 255, 0);
    bf16*  h1c = h1 + (size_t)ch*(R0/2)*512;
    float* c1c = c1 + (size_t)ch*(R0/2)*512;
    const int orows = (int)(R0/2);
    level128_kernel<<<dim3(orows/128, 8), 256, 0, stream>>>(h0, h1c, c0, c1c,
                                                            Uall, Uioub, Ufb);
  }

  // ---- levels 2..8; after each EVEN level, one logits2 covers (lv-1, lv) ----
  // Validity: lv-1's h (h1) is intact until lv+1 writes h1; lv's h (h0) until lv+2.
  for (int lv = 2; lv <= 8; lv++){
    const int rows = 65536 >> lv;
    const bf16*  hin  = (lv & 1) ? h0 : h1;
    bf16*        hout = (lv & 1) ? h1 : h0;
    const float* cin  = (lv & 1) ? c0 : c1;
    float*       cout = (lv & 1) ? c1 : c0;
    if (rows >= 4096)
      level128_kernel<<<dim3(rows/128, 8), 256, 0, stream>>>(hin, hout, cin, cout,
                                                             Uall, Uioub, Ufb);
    else
      level_kernel<<<dim3(rows/64, 8), 256, 0, stream>>>(hin, hout, cin, cout,
                                                         Uall, Uioub, Ufb);
    if ((lv & 1) == 0){
      const int rows_a = 65536 >> (lv-1);        // lv-1 rows (in h1)
      const int rows_b = rows;                   // lv rows   (in h0)
      logits2_kernel<<<(rows_a + rows_b)/4, 256, 0, stream>>>(
          h1, rows_a, 8-(lv-1), (256>>(lv-1))-1, offs[lv-1],
          h0,         8-lv,     (256>>lv)-1,     offs[lv],
          linw, linb, out);
    }
  }
}